// Round 1
// baseline (24.311 us; speedup 1.0000x reference)
//
#include <hip/hip_runtime.h>

#define HEADN   2000
#define NSAMP   100
#define KC      10
#define CLIPV   20.0f
#define BATCH   2048
#define NCLASS  50000
#define TAILSCL 480.0f   // (50000-2000)/100

__device__ __forceinline__ float clipf(float x) {
    return fminf(fmaxf(x, -CLIPV), CLIPV);
}

// softplus(x) = log1p(exp(x)); x is pre-clipped to [-20,20] so exp is safe
__device__ __forceinline__ float sp(float x) {
    return log1pf(expf(x));
}

__global__ __launch_bounds__(256) void row_loss_kernel(
        const float* __restrict__ logits,
        const int*   __restrict__ cand,
        const int*   __restrict__ samp,
        float*       __restrict__ row_out)
{
    const int b   = blockIdx.x;
    const int tid = threadIdx.x;
    const float* lg = logits + (size_t)b * NCLASS;

    float candSum = 0.f;   // sum of clipped logits at distinct valid candidates
    float candCnt = 0.f;   // number of distinct valid candidates
    float acc     = 0.f;   // term2 partial + term3*scale partial

    // ---- Phase A: candidate handling (threads 0..KC-1, one candidate each) ----
    if (tid < KC) {
        const int ci = cand[b * KC + tid];
        if (ci >= 0) {
            // distinct = no earlier equal valid candidate
            bool distinct = true;
            #pragma unroll
            for (int j = 0; j < KC; ++j) {
                int cj = cand[b * KC + j];   // L1-cached broadcast
                if (j < tid && cj >= 0 && cj == ci) distinct = false;
            }
            if (distinct) {
                float x = clipf(lg[ci]);
                candSum = x;
                candCnt = 1.f;
                if (ci < HEADN) acc -= sp(x);  // candidate inside head: masked out of term2
            }
        }
    }

    // ---- Phase B: head softplus sum (unmasked; candidate correction above) ----
    const float4* lg4 = (const float4*)lg;
    #pragma unroll 2
    for (int i = tid; i < HEADN / 4; i += 256) {
        float4 v = lg4[i];
        acc += sp(clipf(v.x)) + sp(clipf(v.y)) + sp(clipf(v.z)) + sp(clipf(v.w));
    }

    // ---- Phase C: sampled tail (threads 0..NSAMP-1, one sample each) ----
    if (tid < NSAMP) {
        const int col = HEADN + samp[tid];
        bool is_cand = false;
        #pragma unroll
        for (int j = 0; j < KC; ++j) {
            int cj = cand[b * KC + j];
            if (cj >= 0 && cj == col) is_cand = true;
        }
        if (!is_cand) acc += TAILSCL * sp(clipf(lg[col]));
    }

    // ---- Reduction: 3 values across 256 threads (4 waves of 64) ----
    #pragma unroll
    for (int off = 32; off > 0; off >>= 1) {
        candSum += __shfl_down(candSum, off);
        candCnt += __shfl_down(candCnt, off);
        acc     += __shfl_down(acc, off);
    }
    __shared__ float s0[4], s1[4], s2[4];
    const int wid = tid >> 6;
    if ((tid & 63) == 0) { s0[wid] = candSum; s1[wid] = candCnt; s2[wid] = acc; }
    __syncthreads();
    if (tid == 0) {
        float cs = s0[0] + s0[1] + s0[2] + s0[3];
        float cc = s1[0] + s1[1] + s1[2] + s1[3];
        float a  = s2[0] + s2[1] + s2[2] + s2[3];
        float avg = cs / fmaxf(cc, 1.f);
        float t1  = log1pf(expf(-avg));     // psi(avg)
        row_out[b] = t1 + a;
    }
}

__global__ __launch_bounds__(256) void mean_kernel(
        const float* __restrict__ row, float* __restrict__ out)
{
    const int tid = threadIdx.x;
    float s = 0.f;
    #pragma unroll 8
    for (int i = tid; i < BATCH; i += 256) s += row[i];
    #pragma unroll
    for (int off = 32; off > 0; off >>= 1) s += __shfl_down(s, off);
    __shared__ float sw[4];
    if ((tid & 63) == 0) sw[tid >> 6] = s;
    __syncthreads();
    if (tid == 0) out[0] = (sw[0] + sw[1] + sw[2] + sw[3]) / (float)BATCH;
}

extern "C" void kernel_launch(void* const* d_in, const int* in_sizes, int n_in,
                              void* d_out, int out_size, void* d_ws, size_t ws_size,
                              hipStream_t stream) {
    const float* logits = (const float*)d_in[0];
    const int*   cand   = (const int*)d_in[1];
    const int*   samp   = (const int*)d_in[2];
    float* row_out = (float*)d_ws;          // BATCH floats of scratch
    float* out     = (float*)d_out;

    row_loss_kernel<<<BATCH, 256, 0, stream>>>(logits, cand, samp, row_out);
    mean_kernel<<<1, 256, 0, stream>>>(row_out, out);
}